// Round 5
// baseline (360.834 us; speedup 1.0000x reference)
//
#include <hip/hip_runtime.h>
#include <stdint.h>
#include <stddef.h>

// SimplifiedLinearAttention on MI355X (gfx950) — FP32 in/out, f16 compute.
// Tolerance 2% relative; single-f16 MFMA (rel err ~2^-11) verified passing.
// R9 changes vs R8 (R8 qkv dbuf REGRESSED: 64KB LDS -> occupancy 28->19.7%,
// overlap didn't pay for the lost block; proj dbuf seemed to help ~7us):
//  * qkv: loop reverted to R7 single-buffer (32KB, ~97us proven).
//  * qkv q-class epilogue: LDS bounce. acc -> Af/Wf (dead after K-loop) with
//    3-bit XOR swizzle byte ^= ((row>>2)&7)<<4 (2-way write, even read),
//    then 8x 16B global stores/thread instead of 64x 2B scalar stores
//    (WRITE_SIZE 197 -> ~155MB, VMEM issue pressure 8x down).
//  * attn: qa (epilogue q tile) loads hoisted to kernel top, issued with the
//    async16 staging — B1's vmcnt drain hides the ~500cy HBM latency that
//    previously sat on the post-B2 critical path.
//  * proj: keeps R8 dbuf 2-phase (latency-bound at grid 1536; R8 delta
//    suggests ~-7us).

typedef _Float16 f16;
typedef __attribute__((ext_vector_type(4))) _Float16 f16x4;
typedef __attribute__((ext_vector_type(8))) _Float16 f16x8;
typedef __attribute__((ext_vector_type(4))) float floatx4;

#define DEV __device__ __forceinline__

DEV void async16(const void* g, void* l) {
  __builtin_amdgcn_global_load_lds(
      (const __attribute__((address_space(1))) void*)g,
      (__attribute__((address_space(3))) void*)l,
      16, 0, 0);
}

DEV floatx4 mfma16(f16x8 a, f16x8 b, floatx4 c) {
  return __builtin_amdgcn_mfma_f32_16x16x32_f16(a, b, c, 0, 0, 0);
}

DEV f16x4 cvt4(float4 v) {
  f16x4 h;
  h[0] = (f16)v.x; h[1] = (f16)v.y; h[2] = (f16)v.z; h[3] = (f16)v.w;
  return h;
}

// ---------------------------------------------------------------------------
// K0: bulk fp32 -> f16 convert (grid-stride, float4 in / f16x4 out).
// ---------------------------------------------------------------------------
__global__ __launch_bounds__(256) void cvt_kernel(
    const float* __restrict__ src, f16* __restrict__ dst, int n4) {
  const int stride = gridDim.x * 256;
  for (int i = blockIdx.x * 256 + threadIdx.x; i < n4; i += stride) {
    float4 v = ((const float4*)src)[i];
    ((f16x4*)dst)[i] = cvt4(v);
  }
}

// ---------------------------------------------------------------------------
// K1: qkv GEMM, A/W pre-converted f16. grid 4608. bx = 72a + 8n + c ->
// m-tile 8a+c, n-tile n: same-m blocks share XCD for L2 reuse of the x tile.
// BK=64; tiles [128][64] f16 linear in LDS (global_load_lds), source-side
// XOR swizzle col16 ^= (row&7); frag reads apply the same XOR (2-way free).
// Single-buffer R7 loop; q-class epilogue bounces through Af/Wf for 16B
// coalesced stores.
// ---------------------------------------------------------------------------
__global__ __launch_bounds__(256) void qkv_kernel(
    const f16* __restrict__ A, const f16* __restrict__ W,
    const float* __restrict__ bias, const float* __restrict__ pos,
    f16* __restrict__ q_ws, f16* __restrict__ kT_ws, f16* __restrict__ vT_ws) {
  __shared__ __align__(16) f16 Af[128 * 64];
  __shared__ __align__(16) f16 Wf[128 * 64];
  const int tid = threadIdx.x;
  const int lane = tid & 63, wave = tid >> 6;
  const int quad = lane >> 4, lr = lane & 15;
  const int wm = wave >> 1, wn = wave & 1;
  const int bx = blockIdx.x;
  const int ga = bx / 72, rem = bx - ga * 72;
  const int nblk = rem >> 3, gc = rem & 7;
  const int m0 = (ga * 8 + gc) * 128, n0 = nblk * 128;
  const int rl = lane >> 3;           // row within 8-row chunk
  const int lcol = (lane & 7) ^ rl;   // logical col16 for this lane's LDS slot

  floatx4 acc[4][4] = {};

  // per-lane global base pointers for the 4 staged chunks (each wave: 4A+4W)
  const f16* ap[4];
  const f16* wp[4];
#pragma unroll
  for (int t2 = 0; t2 < 4; ++t2) {
    const int row = (wave * 4 + t2) * 8 + rl;
    ap[t2] = A + (size_t)(m0 + row) * 384 + lcol * 8;
    wp[t2] = W + (size_t)(n0 + row) * 384 + lcol * 8;
  }

  for (int kt = 0; kt < 6; ++kt) {
    __syncthreads();  // prior frag reads done
#pragma unroll
    for (int t2 = 0; t2 < 4; ++t2) {
      const int ch = wave * 4 + t2;
      async16(ap[t2] + kt * 64, (char*)Af + ch * 1024);
      async16(wp[t2] + kt * 64, (char*)Wf + ch * 1024);
    }
    __syncthreads();  // compiler drains vmcnt before s_barrier
#pragma unroll
    for (int s = 0; s < 2; ++s) {
      const int pc = ((quad + s * 4) ^ (lr & 7)) * 16;  // swizzled col byte
      f16x8 af[4], wf[4];
#pragma unroll
      for (int mt = 0; mt < 4; ++mt)
        af[mt] = *(const f16x8*)((const char*)Af +
                                 (wm * 64 + mt * 16 + lr) * 128 + pc);
#pragma unroll
      for (int nt = 0; nt < 4; ++nt)
        wf[nt] = *(const f16x8*)((const char*)Wf +
                                 (wn * 64 + nt * 16 + lr) * 128 + pc);
#pragma unroll
      for (int mt = 0; mt < 4; ++mt)
#pragma unroll
        for (int nt = 0; nt < 4; ++nt)
          acc[mt][nt] = mfma16(af[mt], wf[nt], acc[mt][nt]);
    }
  }

  float bv[4];
#pragma unroll
  for (int nt = 0; nt < 4; ++nt)
    bv[nt] = bias[n0 + wn * 64 + nt * 16 + lr];

  const int cls = nblk / 3;                 // 0=q 1=k 2=v
  const int cbase = (nblk - cls * 3) * 128; // channel base within class
  if (cls == 0) {
    // ---- q epilogue: bounce via LDS for coalesced 16B stores ----
    __syncthreads();  // all frag reads of the last tile done; Af/Wf reusable
    // bounce layout: half wn -> buf [128 rows][64 f16]=128B/row; byte-in-row
    // = (cl*2) ^ (((row>>2)&7)<<4). Write inst: 4 quad-rows -> 4 distinct
    // 16B slots (2-way dword merge only).
    f16* buf = wn ? Wf : Af;
#pragma unroll
    for (int mt = 0; mt < 4; ++mt) {
#pragma unroll
      for (int nt = 0; nt < 4; ++nt) {
#pragma unroll
        for (int r = 0; r < 4; ++r) {
          const int row = wm * 64 + mt * 16 + quad * 4 + r;
          const int cb = ((nt * 16 + lr) * 2) ^ (((row >> 2) & 7) << 4);
          const float val = fmaxf(acc[mt][nt][r] + bv[nt], 0.f);
          *(f16*)((char*)buf + row * 128 + cb) = (f16)val;
        }
      }
    }
    __syncthreads();
    // read-back: thread -> row t=tid>>1, heads {2(tid&1), 2(tid&1)+1};
    // each head-chunk = 64B = 4 x 16B (same XOR), stored contiguously.
    const int t = tid >> 1;
    const int tg = (m0 & 255) + t;
    const int bwin = m0 >> 8;
    const int hbase = nblk * 4;
    const int sw = ((t >> 2) & 7) << 4;
    const char* arow = (const char*)Af + t * 128;
    const char* wrow = (const char*)Wf + t * 128;
#pragma unroll
    for (int hh = 0; hh < 2; ++hh) {
      const int h = (tid & 1) * 2 + hh;           // head-quarter 0..3
      const char* src = (h & 2) ? wrow : arow;    // ch 0-63 Af, 64-127 Wf
      const int off0 = (h & 1) * 64;              // byte base within half
      f16* dst = q_ws + (size_t)(bwin * 12 + hbase + h) * 8192 + tg * 32;
#pragma unroll
      for (int s = 0; s < 4; ++s)
        *(f16x8*)(dst + s * 8) = *(const f16x8*)(src + ((off0 + s * 16) ^ sw));
    }
  } else {
#pragma unroll
    for (int mt = 0; mt < 4; ++mt) {
      const int mb = m0 + wm * 64 + mt * 16 + quad * 4;  // token base (4 consec)
      const int bwin = mb >> 8, t0 = mb & 255;
#pragma unroll
      for (int nt = 0; nt < 4; ++nt) {
        const int c = cbase + wn * 64 + nt * 16 + lr;
        const int h = c >> 5, hd = c & 31;
        f16x4 pk;
        if (cls == 1) {
#pragma unroll
          for (int r = 0; r < 4; ++r)
            pk[r] = (f16)fmaxf(acc[mt][nt][r] + bv[nt] + pos[(t0 + r) * 384 + c], 0.f);
          *(f16x4*)(kT_ws + (size_t)(bwin * 12 + h) * 8192 + hd * 256 + t0) = pk;
        } else {
#pragma unroll
          for (int r = 0; r < 4; ++r)
            pk[r] = (f16)(acc[mt][nt][r] + bv[nt]);
          *(f16x4*)(vT_ws + (size_t)(bwin * 12 + h) * 8192 + hd * 256 + t0) = pk;
        }
      }
    }
  }
}

// ---------------------------------------------------------------------------
// K2: attention + dwc. One block per (window,head), 256 threads, 4 waves.
// Staged-LDS; kv partitioned by OUTPUT fragment across waves (wave w:
// m2=w&1, n2=w>>1, full K=256) -> no pkv, no cross-wave reduce, 2 barriers.
// qa (epilogue q tile) prefetched into regs at kernel top (hidden by B1).
// ksum finalized per-wave; z from qa frags. LDS 38400 B.
// ---------------------------------------------------------------------------
__global__ __launch_bounds__(256) void attn_kernel(
    const f16* __restrict__ q_ws, const f16* __restrict__ kT_ws,
    const f16* __restrict__ vT_ws, const float* __restrict__ dwc_w,
    const float* __restrict__ dwc_b, f16* __restrict__ y_ws) {
  __shared__ __align__(16) char khb[16640];   // kT chunks; later fm [256][32] f16
  __shared__ __align__(16) char vhb[16640];   // vT chunks
  __shared__ float psum[8 * 32];              // ksum partials
  __shared__ float ksum[4][32];               // per-wave final k column sums
  __shared__ float zbuf[256];                 // z_i (wave-local rows)
  __shared__ __align__(16) f16 kvT[32 * 40];  // kv^T [d][c], pad 40

  const int tid = threadIdx.x;
  const int lane = tid & 63, wave = tid >> 6;
  const int quad = lane >> 4, lr = lane & 15;
  const size_t base = (size_t)blockIdx.x * 8192;

  // ---- stage kT, vT (channel c at (c>>1)*1040 + (c&1)*512 bytes) ----
#pragma unroll
  for (int t2 = 0; t2 < 4; ++t2) {
    const int is = wave * 4 + t2;
    async16(kT_ws + base + is * 512 + lane * 8, khb + is * 1040);
    async16(vT_ws + base + is * 512 + lane * 8, vhb + is * 1040);
  }
  // ---- early q prefetch (regs): latency hidden by B1's staging drain.
  // Wave-local y-alias safety: each wave reads only its own 64-row slab,
  // which only itself overwrites (in the epilogue, after these regs load).
  f16x8 qa[4];
#pragma unroll
  for (int mm = 0; mm < 4; ++mm)
    qa[mm] = *(const f16x8*)(q_ws + base +
                             (size_t)(wave * 64 + mm * 16 + lr) * 32 + quad * 8);
  __syncthreads();  // B1

  // ---- ksum partials: thread (c=tid&31, seg=tid>>5) sums 32 tokens ----
  {
    const int c = tid & 31, seg = tid >> 5;
    const char* kr = khb + (c >> 1) * 1040 + (c & 1) * 512;
    float s = 0.f;
#pragma unroll
    for (int j8 = 0; j8 < 32; j8 += 8) {
      f16x8 a = *(const f16x8*)(kr + (seg * 32 + j8) * 2);
#pragma unroll
      for (int j = 0; j < 8; ++j) s += (float)a[j];
    }
    psum[seg * 32 + c] = s;
  }
  // ---- kv fragment (m2=wave&1, n2=wave>>1) over full K=256 ----
  {
    const int m2 = wave & 1, n2 = wave >> 1;
    const int ck = m2 * 16 + lr, cv = n2 * 16 + lr;
    const char* krow = khb + (ck >> 1) * 1040 + (ck & 1) * 512;
    const char* vrow = vhb + (cv >> 1) * 1040 + (cv & 1) * 512;
    floatx4 kacc = {};
#pragma unroll
    for (int s = 0; s < 8; ++s) {
      f16x8 ka = *(const f16x8*)(krow + (s * 32 + quad * 8) * 2);
      f16x8 vb = *(const f16x8*)(vrow + (s * 32 + quad * 8) * 2);
      kacc = mfma16(ka, vb, kacc);
    }
    // C layout: row c = m2*16 + quad*4 + r, col d = n2*16 + lr.
    f16x4 kk;
#pragma unroll
    for (int r = 0; r < 4; ++r) kk[r] = (f16)kacc[r];
    *(f16x4*)(kvT + (n2 * 16 + lr) * 40 + m2 * 16 + quad * 4) = kk;
  }
  __syncthreads();  // B2 — khb/vhb reads + psum + kvT writes done

  // ---- ksum final (each wave, redundant; lanes 0..31) ----
  if (lane < 32) {
    float s = 0.f;
#pragma unroll
    for (int seg = 0; seg < 8; ++seg) s += psum[seg * 32 + lane];
    ksum[wave][lane] = s;
  }

  // ---- dwc (fp32): thread owns channels {2cg,2cg+1}, w-row xr = wave*4+quad
  // -> writes fm pixels [wave*64, wave*64+64): wave-local. fm overwrites khb.
  {
    uint32_t* fmu = (uint32_t*)khb;  // fm [256 pix][16 pairs] packed 2xf16
    const int cg = lr, xr = wave * 4 + quad, c0 = cg * 2;
    float a0[16], a1[16];
    const float b0v = dwc_b[c0], b1v = dwc_b[c0 + 1];
#pragma unroll
    for (int yy = 0; yy < 16; ++yy) { a0[yy] = b0v; a1[yy] = b1v; }
    const char* v0 = vhb + cg * 1040;  // channel c0 (even); +512 -> c0+1
#pragma unroll
    for (int dx = 0; dx < 5; ++dx) {
      const int xx = xr + dx - 2;
      if (xx < 0 || xx > 15) continue;
      float r0[16], r1[16];
      f16x8 h0 = *(const f16x8*)(v0 + xx * 32);
      f16x8 h1 = *(const f16x8*)(v0 + xx * 32 + 16);
      f16x8 h2 = *(const f16x8*)(v0 + 512 + xx * 32);
      f16x8 h3 = *(const f16x8*)(v0 + 512 + xx * 32 + 16);
#pragma unroll
      for (int j = 0; j < 8; ++j) {
        r0[j] = (float)h0[j]; r0[8 + j] = (float)h1[j];
        r1[j] = (float)h2[j]; r1[8 + j] = (float)h3[j];
      }
#pragma unroll
      for (int dy = 0; dy < 5; ++dy) {
        const float w0 = dwc_w[c0 * 25 + dx * 5 + dy];
        const float w1 = dwc_w[(c0 + 1) * 25 + dx * 5 + dy];
#pragma unroll
        for (int yy = 0; yy < 16; ++yy) {
          const int ys = yy + dy - 2;
          if (ys >= 0 && ys < 16) {
            a0[yy] += w0 * r0[ys];
            a1[yy] += w1 * r1[ys];
          }
        }
      }
    }
#pragma unroll
    for (int yy = 0; yy < 16; ++yy) {
      const uint32_t lo = (uint32_t)__builtin_bit_cast(uint16_t, (f16)a0[yy]);
      const uint32_t hi = (uint32_t)__builtin_bit_cast(uint16_t, (f16)a1[yy]);
      fmu[(xr * 16 + yy) * 16 + cg] = lo | (hi << 16);
    }
  }

  // ---- out = z*(q@kv) + fm -> y (aliases q; wave-local rows) ----
  {
    // z from qa frags: channels quad*8..+7; reduce over quads via shfl_xor.
    float ksv[8];
#pragma unroll
    for (int j = 0; j < 8; ++j) ksv[j] = ksum[wave][quad * 8 + j];
#pragma unroll
    for (int mm = 0; mm < 4; ++mm) {
      float dot = 0.f;
#pragma unroll
      for (int j = 0; j < 8; ++j) dot += (float)qa[mm][j] * ksv[j];
      dot += __shfl_xor(dot, 16);
      dot += __shfl_xor(dot, 32);
      if (quad == 0) zbuf[wave * 64 + mm * 16 + lr] = 1.f / (dot + 1e-6f);
    }

    floatx4 oacc[4][2] = {};
    f16x8 kb[2];
#pragma unroll
    for (int nt = 0; nt < 2; ++nt)
      kb[nt] = *(const f16x8*)(kvT + (nt * 16 + lr) * 40 + quad * 8);
#pragma unroll
    for (int mm = 0; mm < 4; ++mm)
#pragma unroll
      for (int nt = 0; nt < 2; ++nt)
        oacc[mm][nt] = mfma16(qa[mm], kb[nt], oacc[mm][nt]);

    const f16* fmb = (const f16*)khb;
#pragma unroll
    for (int mm = 0; mm < 4; ++mm) {
#pragma unroll
      for (int r = 0; r < 4; ++r) {
        const int i = wave * 64 + mm * 16 + quad * 4 + r;
        const float zi = zbuf[i];
#pragma unroll
        for (int nt = 0; nt < 2; ++nt) {
          const int d = nt * 16 + lr;
          const float val = oacc[mm][nt][r] * zi + (float)fmb[i * 32 + d];
          y_ws[base + (size_t)i * 32 + d] = (f16)val;
        }
      }
    }
  }
}

// ---------------------------------------------------------------------------
// K3: out = y @ proj_w^T + proj_b (fp32 out). grid 1536, bx = 24a + 8n + c.
// BK=64: each K-tile covers TWO heads of y via per-lane source addresses
// (y layout [head][token][32] f16). Dbuf + 2-phase prefetch (kept from R8);
// W pre-converted f16 (pwh, kT region); same XOR source swizzle.
// ---------------------------------------------------------------------------
__global__ __launch_bounds__(256) void proj_kernel(
    const f16* __restrict__ Y, const f16* __restrict__ Wh,
    const float* __restrict__ bias, float* __restrict__ out) {
  __shared__ __align__(16) f16 Af[2][128 * 64];
  __shared__ __align__(16) f16 Wf[2][128 * 64];
  const int tid = threadIdx.x;
  const int lane = tid & 63, wave = tid >> 6;
  const int quad = lane >> 4, lr = lane & 15;
  const int wm = wave >> 1, wn = wave & 1;
  const int bx = blockIdx.x;
  const int ga = bx / 24, rem = bx - ga * 24;
  const int nblk = rem >> 3, gc = rem & 7;
  const int m0 = (ga * 8 + gc) * 128, n0 = nblk * 128;
  const int bwin = m0 >> 8, tbase = m0 & 255;
  const int rl = lane >> 3;
  const int lcol = (lane & 7) ^ rl;   // logical col16: 0..3 head 2kt, 4..7 head 2kt+1

  floatx4 acc[4][4] = {};

  const f16* ap[4];  // head-pair stride per kt: 2*8192 f16
  const f16* wp[4];
#pragma unroll
  for (int t2 = 0; t2 < 4; ++t2) {
    const int rowl = (wave * 4 + t2) * 8 + rl;
    ap[t2] = Y + (size_t)(bwin * 12 + (lcol >> 2)) * 8192 +
             (size_t)(tbase + rowl) * 32 + (lcol & 3) * 8;
    wp[t2] = Wh + (size_t)(n0 + rowl) * 384 + lcol * 8;
  }

  // prologue: stage kt=0 -> buf 0
#pragma unroll
  for (int t2 = 0; t2 < 4; ++t2) {
    const int ch = wave * 4 + t2;
    async16(ap[t2], (char*)Af[0] + ch * 1024);
    async16(wp[t2], (char*)Wf[0] + ch * 1024);
  }
  __syncthreads();

#pragma unroll
  for (int kt = 0; kt < 6; ++kt) {
    const int p = kt & 1;
    if (kt < 5) {  // issue stage(kt+1) -> buf[p^1] BEFORE compute
#pragma unroll
      for (int t2 = 0; t2 < 4; ++t2) {
        const int ch = wave * 4 + t2;
        async16(ap[t2] + (size_t)(kt + 1) * 16384, (char*)Af[p ^ 1] + ch * 1024);
        async16(wp[t2] + (kt + 1) * 64, (char*)Wf[p ^ 1] + ch * 1024);
      }
    }
#pragma unroll
    for (int s = 0; s < 2; ++s) {
      const int pc = ((quad + s * 4) ^ (lr & 7)) * 16;
      f16x8 af[4], wf[4];
#pragma unroll
      for (int mt = 0; mt < 4; ++mt)
        af[mt] = *(const f16x8*)((const char*)Af[p] +
                                 (wm * 64 + mt * 16 + lr) * 128 + pc);
#pragma unroll
      for (int nt = 0; nt < 4; ++nt)
        wf[nt] = *(const f16x8*)((const char*)Wf[p] +
                                 (wn * 64 + nt * 16 + lr) * 128 + pc);
#pragma unroll
      for (int mt = 0; mt < 4; ++mt)
#pragma unroll
        for (int nt = 0; nt < 4; ++nt)
          acc[mt][nt] = mfma16(af[mt], wf[nt], acc[mt][nt]);
    }
    __syncthreads();
  }

  float bv[4];
#pragma unroll
  for (int nt = 0; nt < 4; ++nt)
    bv[nt] = bias[n0 + wn * 64 + nt * 16 + lr];
#pragma unroll
  for (int mt = 0; mt < 4; ++mt)
#pragma unroll
    for (int r = 0; r < 4; ++r) {
      const int m = m0 + wm * 64 + mt * 16 + quad * 4 + r;
#pragma unroll
      for (int nt = 0; nt < 4; ++nt) {
        const int n = n0 + wn * 64 + nt * 16 + lr;
        out[(size_t)m * 384 + n] = acc[mt][nt][r] + bv[nt];
      }
    }
}

// ---------------------------------------------------------------------------
extern "C" void kernel_launch(void* const* d_in, const int* in_sizes, int n_in,
                              void* d_out, int out_size, void* d_ws, size_t ws_size,
                              hipStream_t stream) {
  const float* x = (const float*)d_in[0];
  const float* qkv_w = (const float*)d_in[1];
  const float* qkv_b = (const float*)d_in[2];
  const float* pos = (const float*)d_in[3];
  const float* dwc_w = (const float*)d_in[4];
  const float* dwc_b = (const float*)d_in[5];
  const float* proj_w = (const float*)d_in[6];
  const float* proj_b = (const float*)d_in[7];
  float* out = (float*)d_out;

  // ws: q/y @0, kT @50331648, vT @100663296; total 150994944 B (144 MiB)
  const size_t WS_NEEDED = 150994944;
  if (ws_size < WS_NEEDED) return;  // diagnostic: absmax stays 1.1328125

  char* ws = (char*)d_ws;
  f16* q_ws = (f16*)(ws);                  // [3072][256][32], later y
  f16* kT_ws = (f16*)(ws + 50331648);      // [3072][32][256]
  f16* vT_ws = (f16*)(ws + 100663296);     // [3072][32][256]

  // f16 staging areas inside d_out (100.6 MB): xh [65536][384] = 50.3 MB,
  // qwh [1152][384] = 0.88 MB. Both dead before proj overwrites d_out.
  f16* xh = (f16*)d_out;
  f16* qwh = (f16*)((char*)d_out + 50331648);
  // proj_w f16 lives in the kT region (dead after attn_kernel).
  f16* pwh = (f16*)(ws + 50331648);

  cvt_kernel<<<2048, 256, 0, stream>>>(x, xh, 6291456);        // 96 MB read
  cvt_kernel<<<432, 256, 0, stream>>>(qkv_w, qwh, 110592);
  qkv_kernel<<<4608, 256, 0, stream>>>(xh, qwh, qkv_b, pos,
                                       q_ws, kT_ws, vT_ws);
  attn_kernel<<<3072, 256, 0, stream>>>(q_ws, kT_ws, vT_ws,
                                        dwc_w, dwc_b, q_ws /* y aliases q */);
  cvt_kernel<<<144, 256, 0, stream>>>(proj_w, pwh, 36864);
  proj_kernel<<<1536, 256, 0, stream>>>(q_ws, pwh, proj_b, out);
}

// Round 6
// 354.247 us; speedup vs baseline: 1.0186x; 1.0186x over previous
//
#include <hip/hip_runtime.h>
#include <stdint.h>
#include <stddef.h>

// SimplifiedLinearAttention on MI355X (gfx950) — FP32 in/out, f16 compute.
// Tolerance 2% relative; single-f16 MFMA (rel err ~2^-11) verified passing.
// R10 changes vs R9 (R9 qkv LDS-bounce REGRESSED +19us: traded bytes on a
// non-bottleneck pipe (HBM 22%) for serialized LDS+barrier work; the real
// cap is 84 VGPR + 64 acc-AGPR = 148 unified -> 3 waves/SIMD = 28% occ):
//  * qkv: q-epilogue reverted to R7 direct scalar stores; kernel widened to
//    8 waves / 512 threads on the SAME 128x128 tile / 32KB LDS / grid 4608.
//    Per-wave output 32x64 -> acc[2][4] = 32 AGPRs (~halved reg footprint)
//    -> ~2x waves/CU for latency hiding. Staging, XOR swizzle, K-loop
//    structure unchanged (wm=wave>>1 slabs, 2 chunks/wave staging).
//  * attn: keeps R9 q-prefetch hoist (~-3us).
//  * proj: keeps R8 dbuf 2-phase (~-7us).

typedef _Float16 f16;
typedef __attribute__((ext_vector_type(4))) _Float16 f16x4;
typedef __attribute__((ext_vector_type(8))) _Float16 f16x8;
typedef __attribute__((ext_vector_type(4))) float floatx4;

#define DEV __device__ __forceinline__

DEV void async16(const void* g, void* l) {
  __builtin_amdgcn_global_load_lds(
      (const __attribute__((address_space(1))) void*)g,
      (__attribute__((address_space(3))) void*)l,
      16, 0, 0);
}

DEV floatx4 mfma16(f16x8 a, f16x8 b, floatx4 c) {
  return __builtin_amdgcn_mfma_f32_16x16x32_f16(a, b, c, 0, 0, 0);
}

DEV f16x4 cvt4(float4 v) {
  f16x4 h;
  h[0] = (f16)v.x; h[1] = (f16)v.y; h[2] = (f16)v.z; h[3] = (f16)v.w;
  return h;
}

// ---------------------------------------------------------------------------
// K0: bulk fp32 -> f16 convert (grid-stride, float4 in / f16x4 out).
// ---------------------------------------------------------------------------
__global__ __launch_bounds__(256) void cvt_kernel(
    const float* __restrict__ src, f16* __restrict__ dst, int n4) {
  const int stride = gridDim.x * 256;
  for (int i = blockIdx.x * 256 + threadIdx.x; i < n4; i += stride) {
    float4 v = ((const float4*)src)[i];
    ((f16x4*)dst)[i] = cvt4(v);
  }
}

// ---------------------------------------------------------------------------
// K1: qkv GEMM, A/W pre-converted f16. grid 4608 x 512 threads (8 waves).
// bx = 72a + 8n + c -> m-tile 8a+c, n-tile n (same-m blocks share XCD).
// BK=64; tiles [128][64] f16 linear in LDS (global_load_lds), source-side
// XOR swizzle col16 ^= (row&7); frag reads apply the same XOR (2-way free).
// Wave w: rows (w>>1)*32..+32 (acc[2][4] = 32 AGPRs), cols (w&1)*64..+64.
// ---------------------------------------------------------------------------
__global__ __launch_bounds__(512) void qkv_kernel(
    const f16* __restrict__ A, const f16* __restrict__ W,
    const float* __restrict__ bias, const float* __restrict__ pos,
    f16* __restrict__ q_ws, f16* __restrict__ kT_ws, f16* __restrict__ vT_ws) {
  __shared__ __align__(16) f16 Af[128 * 64];
  __shared__ __align__(16) f16 Wf[128 * 64];
  const int tid = threadIdx.x;
  const int lane = tid & 63, wave = tid >> 6;   // 8 waves
  const int quad = lane >> 4, lr = lane & 15;
  const int wm = wave >> 1, wn = wave & 1;      // wm 0..3 (32-row slab)
  const int bx = blockIdx.x;
  const int ga = bx / 72, rem = bx - ga * 72;
  const int nblk = rem >> 3, gc = rem & 7;
  const int m0 = (ga * 8 + gc) * 128, n0 = nblk * 128;
  const int rl = lane >> 3;           // row within 8-row chunk
  const int lcol = (lane & 7) ^ rl;   // logical col16 for this lane's LDS slot

  floatx4 acc[2][4] = {};

  // per-lane global base pointers: each wave stages 2 A-chunks + 2 W-chunks
  const f16* ap[2];
  const f16* wp[2];
#pragma unroll
  for (int t2 = 0; t2 < 2; ++t2) {
    const int row = (wave * 2 + t2) * 8 + rl;
    ap[t2] = A + (size_t)(m0 + row) * 384 + lcol * 8;
    wp[t2] = W + (size_t)(n0 + row) * 384 + lcol * 8;
  }

  for (int kt = 0; kt < 6; ++kt) {
    __syncthreads();  // prior frag reads done
#pragma unroll
    for (int t2 = 0; t2 < 2; ++t2) {
      const int ch = wave * 2 + t2;
      async16(ap[t2] + kt * 64, (char*)Af + ch * 1024);
      async16(wp[t2] + kt * 64, (char*)Wf + ch * 1024);
    }
    __syncthreads();  // compiler drains vmcnt before s_barrier
#pragma unroll
    for (int s = 0; s < 2; ++s) {
      const int pc = ((quad + s * 4) ^ (lr & 7)) * 16;  // swizzled col byte
      f16x8 af[2], wf[4];
#pragma unroll
      for (int mt = 0; mt < 2; ++mt)
        af[mt] = *(const f16x8*)((const char*)Af +
                                 (wm * 32 + mt * 16 + lr) * 128 + pc);
#pragma unroll
      for (int nt = 0; nt < 4; ++nt)
        wf[nt] = *(const f16x8*)((const char*)Wf +
                                 (wn * 64 + nt * 16 + lr) * 128 + pc);
#pragma unroll
      for (int mt = 0; mt < 2; ++mt)
#pragma unroll
        for (int nt = 0; nt < 4; ++nt)
          acc[mt][nt] = mfma16(af[mt], wf[nt], acc[mt][nt]);
    }
  }

  float bv[4];
#pragma unroll
  for (int nt = 0; nt < 4; ++nt)
    bv[nt] = bias[n0 + wn * 64 + nt * 16 + lr];

  const int cls = nblk / 3;                 // 0=q 1=k 2=v
  const int cbase = (nblk - cls * 3) * 128; // channel base within class
  if (cls == 0) {
#pragma unroll
    for (int mt = 0; mt < 2; ++mt) {
#pragma unroll
      for (int r = 0; r < 4; ++r) {
        const int m = m0 + wm * 32 + mt * 16 + quad * 4 + r;
        const int bwin = m >> 8, t = m & 255;
#pragma unroll
        for (int nt = 0; nt < 4; ++nt) {
          const int c = cbase + wn * 64 + nt * 16 + lr;
          const int h = c >> 5, hd = c & 31;
          const float val = fmaxf(acc[mt][nt][r] + bv[nt], 0.f);
          q_ws[(size_t)(bwin * 12 + h) * 8192 + t * 32 + hd] = (f16)val;
        }
      }
    }
  } else {
#pragma unroll
    for (int mt = 0; mt < 2; ++mt) {
      const int mb = m0 + wm * 32 + mt * 16 + quad * 4;  // token base (4 consec)
      const int bwin = mb >> 8, t0 = mb & 255;
#pragma unroll
      for (int nt = 0; nt < 4; ++nt) {
        const int c = cbase + wn * 64 + nt * 16 + lr;
        const int h = c >> 5, hd = c & 31;
        f16x4 pk;
        if (cls == 1) {
#pragma unroll
          for (int r = 0; r < 4; ++r)
            pk[r] = (f16)fmaxf(acc[mt][nt][r] + bv[nt] + pos[(t0 + r) * 384 + c], 0.f);
          *(f16x4*)(kT_ws + (size_t)(bwin * 12 + h) * 8192 + hd * 256 + t0) = pk;
        } else {
#pragma unroll
          for (int r = 0; r < 4; ++r)
            pk[r] = (f16)(acc[mt][nt][r] + bv[nt]);
          *(f16x4*)(vT_ws + (size_t)(bwin * 12 + h) * 8192 + hd * 256 + t0) = pk;
        }
      }
    }
  }
}

// ---------------------------------------------------------------------------
// K2: attention + dwc. One block per (window,head), 256 threads, 4 waves.
// Staged-LDS; kv partitioned by OUTPUT fragment across waves (wave w:
// m2=w&1, n2=w>>1, full K=256) -> no pkv, no cross-wave reduce, 2 barriers.
// qa (epilogue q tile) prefetched into regs at kernel top (hidden by B1).
// ksum finalized per-wave; z from qa frags. LDS 38400 B.
// ---------------------------------------------------------------------------
__global__ __launch_bounds__(256) void attn_kernel(
    const f16* __restrict__ q_ws, const f16* __restrict__ kT_ws,
    const f16* __restrict__ vT_ws, const float* __restrict__ dwc_w,
    const float* __restrict__ dwc_b, f16* __restrict__ y_ws) {
  __shared__ __align__(16) char khb[16640];   // kT chunks; later fm [256][32] f16
  __shared__ __align__(16) char vhb[16640];   // vT chunks
  __shared__ float psum[8 * 32];              // ksum partials
  __shared__ float ksum[4][32];               // per-wave final k column sums
  __shared__ float zbuf[256];                 // z_i (wave-local rows)
  __shared__ __align__(16) f16 kvT[32 * 40];  // kv^T [d][c], pad 40

  const int tid = threadIdx.x;
  const int lane = tid & 63, wave = tid >> 6;
  const int quad = lane >> 4, lr = lane & 15;
  const size_t base = (size_t)blockIdx.x * 8192;

  // ---- stage kT, vT (channel c at (c>>1)*1040 + (c&1)*512 bytes) ----
#pragma unroll
  for (int t2 = 0; t2 < 4; ++t2) {
    const int is = wave * 4 + t2;
    async16(kT_ws + base + is * 512 + lane * 8, khb + is * 1040);
    async16(vT_ws + base + is * 512 + lane * 8, vhb + is * 1040);
  }
  // ---- early q prefetch (regs): latency hidden by B1's staging drain.
  // Wave-local y-alias safety: each wave reads only its own 64-row slab,
  // which only itself overwrites (in the epilogue, after these regs load).
  f16x8 qa[4];
#pragma unroll
  for (int mm = 0; mm < 4; ++mm)
    qa[mm] = *(const f16x8*)(q_ws + base +
                             (size_t)(wave * 64 + mm * 16 + lr) * 32 + quad * 8);
  __syncthreads();  // B1

  // ---- ksum partials: thread (c=tid&31, seg=tid>>5) sums 32 tokens ----
  {
    const int c = tid & 31, seg = tid >> 5;
    const char* kr = khb + (c >> 1) * 1040 + (c & 1) * 512;
    float s = 0.f;
#pragma unroll
    for (int j8 = 0; j8 < 32; j8 += 8) {
      f16x8 a = *(const f16x8*)(kr + (seg * 32 + j8) * 2);
#pragma unroll
      for (int j = 0; j < 8; ++j) s += (float)a[j];
    }
    psum[seg * 32 + c] = s;
  }
  // ---- kv fragment (m2=wave&1, n2=wave>>1) over full K=256 ----
  {
    const int m2 = wave & 1, n2 = wave >> 1;
    const int ck = m2 * 16 + lr, cv = n2 * 16 + lr;
    const char* krow = khb + (ck >> 1) * 1040 + (ck & 1) * 512;
    const char* vrow = vhb + (cv >> 1) * 1040 + (cv & 1) * 512;
    floatx4 kacc = {};
#pragma unroll
    for (int s = 0; s < 8; ++s) {
      f16x8 ka = *(const f16x8*)(krow + (s * 32 + quad * 8) * 2);
      f16x8 vb = *(const f16x8*)(vrow + (s * 32 + quad * 8) * 2);
      kacc = mfma16(ka, vb, kacc);
    }
    // C layout: row c = m2*16 + quad*4 + r, col d = n2*16 + lr.
    f16x4 kk;
#pragma unroll
    for (int r = 0; r < 4; ++r) kk[r] = (f16)kacc[r];
    *(f16x4*)(kvT + (n2 * 16 + lr) * 40 + m2 * 16 + quad * 4) = kk;
  }
  __syncthreads();  // B2 — khb/vhb reads + psum + kvT writes done

  // ---- ksum final (each wave, redundant; lanes 0..31) ----
  if (lane < 32) {
    float s = 0.f;
#pragma unroll
    for (int seg = 0; seg < 8; ++seg) s += psum[seg * 32 + lane];
    ksum[wave][lane] = s;
  }

  // ---- dwc (fp32): thread owns channels {2cg,2cg+1}, w-row xr = wave*4+quad
  // -> writes fm pixels [wave*64, wave*64+64): wave-local. fm overwrites khb.
  {
    uint32_t* fmu = (uint32_t*)khb;  // fm [256 pix][16 pairs] packed 2xf16
    const int cg = lr, xr = wave * 4 + quad, c0 = cg * 2;
    float a0[16], a1[16];
    const float b0v = dwc_b[c0], b1v = dwc_b[c0 + 1];
#pragma unroll
    for (int yy = 0; yy < 16; ++yy) { a0[yy] = b0v; a1[yy] = b1v; }
    const char* v0 = vhb + cg * 1040;  // channel c0 (even); +512 -> c0+1
#pragma unroll
    for (int dx = 0; dx < 5; ++dx) {
      const int xx = xr + dx - 2;
      if (xx < 0 || xx > 15) continue;
      float r0[16], r1[16];
      f16x8 h0 = *(const f16x8*)(v0 + xx * 32);
      f16x8 h1 = *(const f16x8*)(v0 + xx * 32 + 16);
      f16x8 h2 = *(const f16x8*)(v0 + 512 + xx * 32);
      f16x8 h3 = *(const f16x8*)(v0 + 512 + xx * 32 + 16);
#pragma unroll
      for (int j = 0; j < 8; ++j) {
        r0[j] = (float)h0[j]; r0[8 + j] = (float)h1[j];
        r1[j] = (float)h2[j]; r1[8 + j] = (float)h3[j];
      }
#pragma unroll
      for (int dy = 0; dy < 5; ++dy) {
        const float w0 = dwc_w[c0 * 25 + dx * 5 + dy];
        const float w1 = dwc_w[(c0 + 1) * 25 + dx * 5 + dy];
#pragma unroll
        for (int yy = 0; yy < 16; ++yy) {
          const int ys = yy + dy - 2;
          if (ys >= 0 && ys < 16) {
            a0[yy] += w0 * r0[ys];
            a1[yy] += w1 * r1[ys];
          }
        }
      }
    }
#pragma unroll
    for (int yy = 0; yy < 16; ++yy) {
      const uint32_t lo = (uint32_t)__builtin_bit_cast(uint16_t, (f16)a0[yy]);
      const uint32_t hi = (uint32_t)__builtin_bit_cast(uint16_t, (f16)a1[yy]);
      fmu[(xr * 16 + yy) * 16 + cg] = lo | (hi << 16);
    }
  }

  // ---- out = z*(q@kv) + fm -> y (aliases q; wave-local rows) ----
  {
    // z from qa frags: channels quad*8..+7; reduce over quads via shfl_xor.
    float ksv[8];
#pragma unroll
    for (int j = 0; j < 8; ++j) ksv[j] = ksum[wave][quad * 8 + j];
#pragma unroll
    for (int mm = 0; mm < 4; ++mm) {
      float dot = 0.f;
#pragma unroll
      for (int j = 0; j < 8; ++j) dot += (float)qa[mm][j] * ksv[j];
      dot += __shfl_xor(dot, 16);
      dot += __shfl_xor(dot, 32);
      if (quad == 0) zbuf[wave * 64 + mm * 16 + lr] = 1.f / (dot + 1e-6f);
    }

    floatx4 oacc[4][2] = {};
    f16x8 kb[2];
#pragma unroll
    for (int nt = 0; nt < 2; ++nt)
      kb[nt] = *(const f16x8*)(kvT + (nt * 16 + lr) * 40 + quad * 8);
#pragma unroll
    for (int mm = 0; mm < 4; ++mm)
#pragma unroll
      for (int nt = 0; nt < 2; ++nt)
        oacc[mm][nt] = mfma16(qa[mm], kb[nt], oacc[mm][nt]);

    const f16* fmb = (const f16*)khb;
#pragma unroll
    for (int mm = 0; mm < 4; ++mm) {
#pragma unroll
      for (int r = 0; r < 4; ++r) {
        const int i = wave * 64 + mm * 16 + quad * 4 + r;
        const float zi = zbuf[i];
#pragma unroll
        for (int nt = 0; nt < 2; ++nt) {
          const int d = nt * 16 + lr;
          const float val = oacc[mm][nt][r] * zi + (float)fmb[i * 32 + d];
          y_ws[base + (size_t)i * 32 + d] = (f16)val;
        }
      }
    }
  }
}

// ---------------------------------------------------------------------------
// K3: out = y @ proj_w^T + proj_b (fp32 out). grid 1536, bx = 24a + 8n + c.
// BK=64: each K-tile covers TWO heads of y via per-lane source addresses
// (y layout [head][token][32] f16). Dbuf + 2-phase prefetch (kept from R8);
// W pre-converted f16 (pwh, kT region); same XOR source swizzle.
// ---------------------------------------------------------------------------
__global__ __launch_bounds__(256) void proj_kernel(
    const f16* __restrict__ Y, const f16* __restrict__ Wh,
    const float* __restrict__ bias, float* __restrict__ out) {
  __shared__ __align__(16) f16 Af[2][128 * 64];
  __shared__ __align__(16) f16 Wf[2][128 * 64];
  const int tid = threadIdx.x;
  const int lane = tid & 63, wave = tid >> 6;
  const int quad = lane >> 4, lr = lane & 15;
  const int wm = wave >> 1, wn = wave & 1;
  const int bx = blockIdx.x;
  const int ga = bx / 24, rem = bx - ga * 24;
  const int nblk = rem >> 3, gc = rem & 7;
  const int m0 = (ga * 8 + gc) * 128, n0 = nblk * 128;
  const int bwin = m0 >> 8, tbase = m0 & 255;
  const int rl = lane >> 3;
  const int lcol = (lane & 7) ^ rl;   // logical col16: 0..3 head 2kt, 4..7 head 2kt+1

  floatx4 acc[4][4] = {};

  const f16* ap[4];  // head-pair stride per kt: 2*8192 f16
  const f16* wp[4];
#pragma unroll
  for (int t2 = 0; t2 < 4; ++t2) {
    const int rowl = (wave * 4 + t2) * 8 + rl;
    ap[t2] = Y + (size_t)(bwin * 12 + (lcol >> 2)) * 8192 +
             (size_t)(tbase + rowl) * 32 + (lcol & 3) * 8;
    wp[t2] = Wh + (size_t)(n0 + rowl) * 384 + lcol * 8;
  }

  // prologue: stage kt=0 -> buf 0
#pragma unroll
  for (int t2 = 0; t2 < 4; ++t2) {
    const int ch = wave * 4 + t2;
    async16(ap[t2], (char*)Af[0] + ch * 1024);
    async16(wp[t2], (char*)Wf[0] + ch * 1024);
  }
  __syncthreads();

#pragma unroll
  for (int kt = 0; kt < 6; ++kt) {
    const int p = kt & 1;
    if (kt < 5) {  // issue stage(kt+1) -> buf[p^1] BEFORE compute
#pragma unroll
      for (int t2 = 0; t2 < 4; ++t2) {
        const int ch = wave * 4 + t2;
        async16(ap[t2] + (size_t)(kt + 1) * 16384, (char*)Af[p ^ 1] + ch * 1024);
        async16(wp[t2] + (kt + 1) * 64, (char*)Wf[p ^ 1] + ch * 1024);
      }
    }
#pragma unroll
    for (int s = 0; s < 2; ++s) {
      const int pc = ((quad + s * 4) ^ (lr & 7)) * 16;
      f16x8 af[4], wf[4];
#pragma unroll
      for (int mt = 0; mt < 4; ++mt)
        af[mt] = *(const f16x8*)((const char*)Af[p] +
                                 (wm * 64 + mt * 16 + lr) * 128 + pc);
#pragma unroll
      for (int nt = 0; nt < 4; ++nt)
        wf[nt] = *(const f16x8*)((const char*)Wf[p] +
                                 (wn * 64 + nt * 16 + lr) * 128 + pc);
#pragma unroll
      for (int mt = 0; mt < 4; ++mt)
#pragma unroll
        for (int nt = 0; nt < 4; ++nt)
          acc[mt][nt] = mfma16(af[mt], wf[nt], acc[mt][nt]);
    }
    __syncthreads();
  }

  float bv[4];
#pragma unroll
  for (int nt = 0; nt < 4; ++nt)
    bv[nt] = bias[n0 + wn * 64 + nt * 16 + lr];
#pragma unroll
  for (int mt = 0; mt < 4; ++mt)
#pragma unroll
    for (int r = 0; r < 4; ++r) {
      const int m = m0 + wm * 64 + mt * 16 + quad * 4 + r;
#pragma unroll
      for (int nt = 0; nt < 4; ++nt) {
        const int n = n0 + wn * 64 + nt * 16 + lr;
        out[(size_t)m * 384 + n] = acc[mt][nt][r] + bv[nt];
      }
    }
}

// ---------------------------------------------------------------------------
extern "C" void kernel_launch(void* const* d_in, const int* in_sizes, int n_in,
                              void* d_out, int out_size, void* d_ws, size_t ws_size,
                              hipStream_t stream) {
  const float* x = (const float*)d_in[0];
  const float* qkv_w = (const float*)d_in[1];
  const float* qkv_b = (const float*)d_in[2];
  const float* pos = (const float*)d_in[3];
  const float* dwc_w = (const float*)d_in[4];
  const float* dwc_b = (const float*)d_in[5];
  const float* proj_w = (const float*)d_in[6];
  const float* proj_b = (const float*)d_in[7];
  float* out = (float*)d_out;

  // ws: q/y @0, kT @50331648, vT @100663296; total 150994944 B (144 MiB)
  const size_t WS_NEEDED = 150994944;
  if (ws_size < WS_NEEDED) return;  // diagnostic: absmax stays 1.1328125

  char* ws = (char*)d_ws;
  f16* q_ws = (f16*)(ws);                  // [3072][256][32], later y
  f16* kT_ws = (f16*)(ws + 50331648);      // [3072][32][256]
  f16* vT_ws = (f16*)(ws + 100663296);     // [3072][32][256]

  // f16 staging areas inside d_out (100.6 MB): xh [65536][384] = 50.3 MB,
  // qwh [1152][384] = 0.88 MB. Both dead before proj overwrites d_out.
  f16* xh = (f16*)d_out;
  f16* qwh = (f16*)((char*)d_out + 50331648);
  // proj_w f16 lives in the kT region (dead after attn_kernel).
  f16* pwh = (f16*)(ws + 50331648);

  cvt_kernel<<<2048, 256, 0, stream>>>(x, xh, 6291456);        // 96 MB read
  cvt_kernel<<<432, 256, 0, stream>>>(qkv_w, qwh, 110592);
  qkv_kernel<<<4608, 512, 0, stream>>>(xh, qwh, qkv_b, pos,
                                       q_ws, kT_ws, vT_ws);
  attn_kernel<<<3072, 256, 0, stream>>>(q_ws, kT_ws, vT_ws,
                                        dwc_w, dwc_b, q_ws /* y aliases q */);
  cvt_kernel<<<144, 256, 0, stream>>>(proj_w, pwh, 36864);
  proj_kernel<<<1536, 256, 0, stream>>>(q_ws, pwh, proj_b, out);
}

// Round 7
// 345.500 us; speedup vs baseline: 1.0444x; 1.0253x over previous
//
#include <hip/hip_runtime.h>
#include <stdint.h>
#include <stddef.h>

// SimplifiedLinearAttention on MI355X (gfx950) — FP32 in/out, f16 compute.
// Tolerance 2% relative; single-f16 MFMA (rel err ~2^-11) verified passing.
// R11 changes vs R10 (R10 widened qkv to 8 waves: occupancy 28->55%, VGPR
// 84->36, but dur flat ~97us -> occupancy wasn't binding; the 1-phase
// barrier drains vmcnt(0) right after issue, exposing ~900cy latency with
// zero compute in between — ~70% stall matches all pipes at ~25%):
//  * qkv: 2-phase LDS double-buffer ON TOP of the 8-wave shape (R8's dbuf
//    failed only via occupancy: 256thr@64KB = 8 waves/CU; 512thr@64KB = 16
//    waves/CU ~ flat). Per K-step: issue stage(kt+1)->buf[p^1], compute
//    buf[p], ONE barrier (drain now sits a full compute-phase after issue).
//  * proj: widened to 512 threads / 8 waves (acc[2][4]) keeping its dbuf:
//    occupancy 19.7% -> ~50% with overlap retained.
//  * attn unchanged (R9 q-hoist version).

typedef _Float16 f16;
typedef __attribute__((ext_vector_type(4))) _Float16 f16x4;
typedef __attribute__((ext_vector_type(8))) _Float16 f16x8;
typedef __attribute__((ext_vector_type(4))) float floatx4;

#define DEV __device__ __forceinline__

DEV void async16(const void* g, void* l) {
  __builtin_amdgcn_global_load_lds(
      (const __attribute__((address_space(1))) void*)g,
      (__attribute__((address_space(3))) void*)l,
      16, 0, 0);
}

DEV floatx4 mfma16(f16x8 a, f16x8 b, floatx4 c) {
  return __builtin_amdgcn_mfma_f32_16x16x32_f16(a, b, c, 0, 0, 0);
}

DEV f16x4 cvt4(float4 v) {
  f16x4 h;
  h[0] = (f16)v.x; h[1] = (f16)v.y; h[2] = (f16)v.z; h[3] = (f16)v.w;
  return h;
}

// ---------------------------------------------------------------------------
// K0: bulk fp32 -> f16 convert (grid-stride, float4 in / f16x4 out).
// ---------------------------------------------------------------------------
__global__ __launch_bounds__(256) void cvt_kernel(
    const float* __restrict__ src, f16* __restrict__ dst, int n4) {
  const int stride = gridDim.x * 256;
  for (int i = blockIdx.x * 256 + threadIdx.x; i < n4; i += stride) {
    float4 v = ((const float4*)src)[i];
    ((f16x4*)dst)[i] = cvt4(v);
  }
}

// ---------------------------------------------------------------------------
// K1: qkv GEMM, A/W pre-converted f16. grid 4608 x 512 threads (8 waves).
// bx = 72a + 8n + c -> m-tile 8a+c, n-tile n (same-m blocks share XCD).
// BK=64; dbuf [2][128][64] f16 linear LDS (global_load_lds), source-side
// XOR swizzle col16 ^= (row&7); frag reads apply the same XOR (2-way free).
// Wave w: rows (w>>1)*32..+32 (acc[2][4] = 32 AGPRs), cols (w&1)*64..+64.
// 2-phase: issue stage(kt+1) -> compute buf[p] -> one barrier per K-step.
// ---------------------------------------------------------------------------
__global__ __launch_bounds__(512) void qkv_kernel(
    const f16* __restrict__ A, const f16* __restrict__ W,
    const float* __restrict__ bias, const float* __restrict__ pos,
    f16* __restrict__ q_ws, f16* __restrict__ kT_ws, f16* __restrict__ vT_ws) {
  __shared__ __align__(16) f16 Af[2][128 * 64];
  __shared__ __align__(16) f16 Wf[2][128 * 64];
  const int tid = threadIdx.x;
  const int lane = tid & 63, wave = tid >> 6;   // 8 waves
  const int quad = lane >> 4, lr = lane & 15;
  const int wm = wave >> 1, wn = wave & 1;      // wm 0..3 (32-row slab)
  const int bx = blockIdx.x;
  const int ga = bx / 72, rem = bx - ga * 72;
  const int nblk = rem >> 3, gc = rem & 7;
  const int m0 = (ga * 8 + gc) * 128, n0 = nblk * 128;
  const int rl = lane >> 3;           // row within 8-row chunk
  const int lcol = (lane & 7) ^ rl;   // logical col16 for this lane's LDS slot

  floatx4 acc[2][4] = {};

  // per-lane global base pointers: each wave stages 2 A-chunks + 2 W-chunks
  const f16* ap[2];
  const f16* wp[2];
#pragma unroll
  for (int t2 = 0; t2 < 2; ++t2) {
    const int row = (wave * 2 + t2) * 8 + rl;
    ap[t2] = A + (size_t)(m0 + row) * 384 + lcol * 8;
    wp[t2] = W + (size_t)(n0 + row) * 384 + lcol * 8;
  }

  // prologue: stage kt=0 -> buf 0
#pragma unroll
  for (int t2 = 0; t2 < 2; ++t2) {
    const int ch = wave * 2 + t2;
    async16(ap[t2], (char*)Af[0] + ch * 1024);
    async16(wp[t2], (char*)Wf[0] + ch * 1024);
  }
  __syncthreads();

#pragma unroll
  for (int kt = 0; kt < 6; ++kt) {
    const int p = kt & 1;
    if (kt < 5) {  // issue stage(kt+1) BEFORE compute; drain sits after it
#pragma unroll
      for (int t2 = 0; t2 < 2; ++t2) {
        const int ch = wave * 2 + t2;
        async16(ap[t2] + (kt + 1) * 64, (char*)Af[p ^ 1] + ch * 1024);
        async16(wp[t2] + (kt + 1) * 64, (char*)Wf[p ^ 1] + ch * 1024);
      }
    }
#pragma unroll
    for (int s = 0; s < 2; ++s) {
      const int pc = ((quad + s * 4) ^ (lr & 7)) * 16;  // swizzled col byte
      f16x8 af[2], wf[4];
#pragma unroll
      for (int mt = 0; mt < 2; ++mt)
        af[mt] = *(const f16x8*)((const char*)Af[p] +
                                 (wm * 32 + mt * 16 + lr) * 128 + pc);
#pragma unroll
      for (int nt = 0; nt < 4; ++nt)
        wf[nt] = *(const f16x8*)((const char*)Wf[p] +
                                 (wn * 64 + nt * 16 + lr) * 128 + pc);
#pragma unroll
      for (int mt = 0; mt < 2; ++mt)
#pragma unroll
        for (int nt = 0; nt < 4; ++nt)
          acc[mt][nt] = mfma16(af[mt], wf[nt], acc[mt][nt]);
    }
    __syncthreads();  // buf[p] reads done; prefetch (vmcnt) drained
  }

  float bv[4];
#pragma unroll
  for (int nt = 0; nt < 4; ++nt)
    bv[nt] = bias[n0 + wn * 64 + nt * 16 + lr];

  const int cls = nblk / 3;                 // 0=q 1=k 2=v
  const int cbase = (nblk - cls * 3) * 128; // channel base within class
  if (cls == 0) {
#pragma unroll
    for (int mt = 0; mt < 2; ++mt) {
#pragma unroll
      for (int r = 0; r < 4; ++r) {
        const int m = m0 + wm * 32 + mt * 16 + quad * 4 + r;
        const int bwin = m >> 8, t = m & 255;
#pragma unroll
        for (int nt = 0; nt < 4; ++nt) {
          const int c = cbase + wn * 64 + nt * 16 + lr;
          const int h = c >> 5, hd = c & 31;
          const float val = fmaxf(acc[mt][nt][r] + bv[nt], 0.f);
          q_ws[(size_t)(bwin * 12 + h) * 8192 + t * 32 + hd] = (f16)val;
        }
      }
    }
  } else {
#pragma unroll
    for (int mt = 0; mt < 2; ++mt) {
      const int mb = m0 + wm * 32 + mt * 16 + quad * 4;  // token base (4 consec)
      const int bwin = mb >> 8, t0 = mb & 255;
#pragma unroll
      for (int nt = 0; nt < 4; ++nt) {
        const int c = cbase + wn * 64 + nt * 16 + lr;
        const int h = c >> 5, hd = c & 31;
        f16x4 pk;
        if (cls == 1) {
#pragma unroll
          for (int r = 0; r < 4; ++r)
            pk[r] = (f16)fmaxf(acc[mt][nt][r] + bv[nt] + pos[(t0 + r) * 384 + c], 0.f);
          *(f16x4*)(kT_ws + (size_t)(bwin * 12 + h) * 8192 + hd * 256 + t0) = pk;
        } else {
#pragma unroll
          for (int r = 0; r < 4; ++r)
            pk[r] = (f16)(acc[mt][nt][r] + bv[nt]);
          *(f16x4*)(vT_ws + (size_t)(bwin * 12 + h) * 8192 + hd * 256 + t0) = pk;
        }
      }
    }
  }
}

// ---------------------------------------------------------------------------
// K2: attention + dwc. One block per (window,head), 256 threads, 4 waves.
// Staged-LDS; kv partitioned by OUTPUT fragment across waves (wave w:
// m2=w&1, n2=w>>1, full K=256) -> no pkv, no cross-wave reduce, 2 barriers.
// qa (epilogue q tile) prefetched into regs at kernel top (hidden by B1).
// ksum finalized per-wave; z from qa frags. LDS 38400 B.
// ---------------------------------------------------------------------------
__global__ __launch_bounds__(256) void attn_kernel(
    const f16* __restrict__ q_ws, const f16* __restrict__ kT_ws,
    const f16* __restrict__ vT_ws, const float* __restrict__ dwc_w,
    const float* __restrict__ dwc_b, f16* __restrict__ y_ws) {
  __shared__ __align__(16) char khb[16640];   // kT chunks; later fm [256][32] f16
  __shared__ __align__(16) char vhb[16640];   // vT chunks
  __shared__ float psum[8 * 32];              // ksum partials
  __shared__ float ksum[4][32];               // per-wave final k column sums
  __shared__ float zbuf[256];                 // z_i (wave-local rows)
  __shared__ __align__(16) f16 kvT[32 * 40];  // kv^T [d][c], pad 40

  const int tid = threadIdx.x;
  const int lane = tid & 63, wave = tid >> 6;
  const int quad = lane >> 4, lr = lane & 15;
  const size_t base = (size_t)blockIdx.x * 8192;

  // ---- stage kT, vT (channel c at (c>>1)*1040 + (c&1)*512 bytes) ----
#pragma unroll
  for (int t2 = 0; t2 < 4; ++t2) {
    const int is = wave * 4 + t2;
    async16(kT_ws + base + is * 512 + lane * 8, khb + is * 1040);
    async16(vT_ws + base + is * 512 + lane * 8, vhb + is * 1040);
  }
  // ---- early q prefetch (regs): latency hidden by B1's staging drain.
  f16x8 qa[4];
#pragma unroll
  for (int mm = 0; mm < 4; ++mm)
    qa[mm] = *(const f16x8*)(q_ws + base +
                             (size_t)(wave * 64 + mm * 16 + lr) * 32 + quad * 8);
  __syncthreads();  // B1

  // ---- ksum partials: thread (c=tid&31, seg=tid>>5) sums 32 tokens ----
  {
    const int c = tid & 31, seg = tid >> 5;
    const char* kr = khb + (c >> 1) * 1040 + (c & 1) * 512;
    float s = 0.f;
#pragma unroll
    for (int j8 = 0; j8 < 32; j8 += 8) {
      f16x8 a = *(const f16x8*)(kr + (seg * 32 + j8) * 2);
#pragma unroll
      for (int j = 0; j < 8; ++j) s += (float)a[j];
    }
    psum[seg * 32 + c] = s;
  }
  // ---- kv fragment (m2=wave&1, n2=wave>>1) over full K=256 ----
  {
    const int m2 = wave & 1, n2 = wave >> 1;
    const int ck = m2 * 16 + lr, cv = n2 * 16 + lr;
    const char* krow = khb + (ck >> 1) * 1040 + (ck & 1) * 512;
    const char* vrow = vhb + (cv >> 1) * 1040 + (cv & 1) * 512;
    floatx4 kacc = {};
#pragma unroll
    for (int s = 0; s < 8; ++s) {
      f16x8 ka = *(const f16x8*)(krow + (s * 32 + quad * 8) * 2);
      f16x8 vb = *(const f16x8*)(vrow + (s * 32 + quad * 8) * 2);
      kacc = mfma16(ka, vb, kacc);
    }
    // C layout: row c = m2*16 + quad*4 + r, col d = n2*16 + lr.
    f16x4 kk;
#pragma unroll
    for (int r = 0; r < 4; ++r) kk[r] = (f16)kacc[r];
    *(f16x4*)(kvT + (n2 * 16 + lr) * 40 + m2 * 16 + quad * 4) = kk;
  }
  __syncthreads();  // B2 — khb/vhb reads + psum + kvT writes done

  // ---- ksum final (each wave, redundant; lanes 0..31) ----
  if (lane < 32) {
    float s = 0.f;
#pragma unroll
    for (int seg = 0; seg < 8; ++seg) s += psum[seg * 32 + lane];
    ksum[wave][lane] = s;
  }

  // ---- dwc (fp32): thread owns channels {2cg,2cg+1}, w-row xr = wave*4+quad
  {
    uint32_t* fmu = (uint32_t*)khb;  // fm [256 pix][16 pairs] packed 2xf16
    const int cg = lr, xr = wave * 4 + quad, c0 = cg * 2;
    float a0[16], a1[16];
    const float b0v = dwc_b[c0], b1v = dwc_b[c0 + 1];
#pragma unroll
    for (int yy = 0; yy < 16; ++yy) { a0[yy] = b0v; a1[yy] = b1v; }
    const char* v0 = vhb + cg * 1040;  // channel c0 (even); +512 -> c0+1
#pragma unroll
    for (int dx = 0; dx < 5; ++dx) {
      const int xx = xr + dx - 2;
      if (xx < 0 || xx > 15) continue;
      float r0[16], r1[16];
      f16x8 h0 = *(const f16x8*)(v0 + xx * 32);
      f16x8 h1 = *(const f16x8*)(v0 + xx * 32 + 16);
      f16x8 h2 = *(const f16x8*)(v0 + 512 + xx * 32);
      f16x8 h3 = *(const f16x8*)(v0 + 512 + xx * 32 + 16);
#pragma unroll
      for (int j = 0; j < 8; ++j) {
        r0[j] = (float)h0[j]; r0[8 + j] = (float)h1[j];
        r1[j] = (float)h2[j]; r1[8 + j] = (float)h3[j];
      }
#pragma unroll
      for (int dy = 0; dy < 5; ++dy) {
        const float w0 = dwc_w[c0 * 25 + dx * 5 + dy];
        const float w1 = dwc_w[(c0 + 1) * 25 + dx * 5 + dy];
#pragma unroll
        for (int yy = 0; yy < 16; ++yy) {
          const int ys = yy + dy - 2;
          if (ys >= 0 && ys < 16) {
            a0[yy] += w0 * r0[ys];
            a1[yy] += w1 * r1[ys];
          }
        }
      }
    }
#pragma unroll
    for (int yy = 0; yy < 16; ++yy) {
      const uint32_t lo = (uint32_t)__builtin_bit_cast(uint16_t, (f16)a0[yy]);
      const uint32_t hi = (uint32_t)__builtin_bit_cast(uint16_t, (f16)a1[yy]);
      fmu[(xr * 16 + yy) * 16 + cg] = lo | (hi << 16);
    }
  }

  // ---- out = z*(q@kv) + fm -> y (aliases q; wave-local rows) ----
  {
    float ksv[8];
#pragma unroll
    for (int j = 0; j < 8; ++j) ksv[j] = ksum[wave][quad * 8 + j];
#pragma unroll
    for (int mm = 0; mm < 4; ++mm) {
      float dot = 0.f;
#pragma unroll
      for (int j = 0; j < 8; ++j) dot += (float)qa[mm][j] * ksv[j];
      dot += __shfl_xor(dot, 16);
      dot += __shfl_xor(dot, 32);
      if (quad == 0) zbuf[wave * 64 + mm * 16 + lr] = 1.f / (dot + 1e-6f);
    }

    floatx4 oacc[4][2] = {};
    f16x8 kb[2];
#pragma unroll
    for (int nt = 0; nt < 2; ++nt)
      kb[nt] = *(const f16x8*)(kvT + (nt * 16 + lr) * 40 + quad * 8);
#pragma unroll
    for (int mm = 0; mm < 4; ++mm)
#pragma unroll
      for (int nt = 0; nt < 2; ++nt)
        oacc[mm][nt] = mfma16(qa[mm], kb[nt], oacc[mm][nt]);

    const f16* fmb = (const f16*)khb;
#pragma unroll
    for (int mm = 0; mm < 4; ++mm) {
#pragma unroll
      for (int r = 0; r < 4; ++r) {
        const int i = wave * 64 + mm * 16 + quad * 4 + r;
        const float zi = zbuf[i];
#pragma unroll
        for (int nt = 0; nt < 2; ++nt) {
          const int d = nt * 16 + lr;
          const float val = oacc[mm][nt][r] * zi + (float)fmb[i * 32 + d];
          y_ws[base + (size_t)i * 32 + d] = (f16)val;
        }
      }
    }
  }
}

// ---------------------------------------------------------------------------
// K3: out = y @ proj_w^T + proj_b (fp32 out). grid 1536 x 512 threads.
// BK=64: each K-tile covers TWO heads of y via per-lane source addresses.
// Dbuf + 2-phase prefetch; 8 waves (acc[2][4]); same XOR source swizzle.
// ---------------------------------------------------------------------------
__global__ __launch_bounds__(512) void proj_kernel(
    const f16* __restrict__ Y, const f16* __restrict__ Wh,
    const float* __restrict__ bias, float* __restrict__ out) {
  __shared__ __align__(16) f16 Af[2][128 * 64];
  __shared__ __align__(16) f16 Wf[2][128 * 64];
  const int tid = threadIdx.x;
  const int lane = tid & 63, wave = tid >> 6;   // 8 waves
  const int quad = lane >> 4, lr = lane & 15;
  const int wm = wave >> 1, wn = wave & 1;      // wm 0..3 (32-row slab)
  const int bx = blockIdx.x;
  const int ga = bx / 24, rem = bx - ga * 24;
  const int nblk = rem >> 3, gc = rem & 7;
  const int m0 = (ga * 8 + gc) * 128, n0 = nblk * 128;
  const int bwin = m0 >> 8, tbase = m0 & 255;
  const int rl = lane >> 3;
  const int lcol = (lane & 7) ^ rl;   // logical col16: 0..3 head 2kt, 4..7 head 2kt+1

  floatx4 acc[2][4] = {};

  const f16* ap[2];  // head-pair stride per kt: 2*8192 f16
  const f16* wp[2];
#pragma unroll
  for (int t2 = 0; t2 < 2; ++t2) {
    const int rowl = (wave * 2 + t2) * 8 + rl;
    ap[t2] = Y + (size_t)(bwin * 12 + (lcol >> 2)) * 8192 +
             (size_t)(tbase + rowl) * 32 + (lcol & 3) * 8;
    wp[t2] = Wh + (size_t)(n0 + rowl) * 384 + lcol * 8;
  }

  // prologue: stage kt=0 -> buf 0
#pragma unroll
  for (int t2 = 0; t2 < 2; ++t2) {
    const int ch = wave * 2 + t2;
    async16(ap[t2], (char*)Af[0] + ch * 1024);
    async16(wp[t2], (char*)Wf[0] + ch * 1024);
  }
  __syncthreads();

#pragma unroll
  for (int kt = 0; kt < 6; ++kt) {
    const int p = kt & 1;
    if (kt < 5) {  // issue stage(kt+1) -> buf[p^1] BEFORE compute
#pragma unroll
      for (int t2 = 0; t2 < 2; ++t2) {
        const int ch = wave * 2 + t2;
        async16(ap[t2] + (size_t)(kt + 1) * 16384, (char*)Af[p ^ 1] + ch * 1024);
        async16(wp[t2] + (kt + 1) * 64, (char*)Wf[p ^ 1] + ch * 1024);
      }
    }
#pragma unroll
    for (int s = 0; s < 2; ++s) {
      const int pc = ((quad + s * 4) ^ (lr & 7)) * 16;
      f16x8 af[2], wf[4];
#pragma unroll
      for (int mt = 0; mt < 2; ++mt)
        af[mt] = *(const f16x8*)((const char*)Af[p] +
                                 (wm * 32 + mt * 16 + lr) * 128 + pc);
#pragma unroll
      for (int nt = 0; nt < 4; ++nt)
        wf[nt] = *(const f16x8*)((const char*)Wf[p] +
                                 (wn * 64 + nt * 16 + lr) * 128 + pc);
#pragma unroll
      for (int mt = 0; mt < 2; ++mt)
#pragma unroll
        for (int nt = 0; nt < 4; ++nt)
          acc[mt][nt] = mfma16(af[mt], wf[nt], acc[mt][nt]);
    }
    __syncthreads();
  }

  float bv[4];
#pragma unroll
  for (int nt = 0; nt < 4; ++nt)
    bv[nt] = bias[n0 + wn * 64 + nt * 16 + lr];
#pragma unroll
  for (int mt = 0; mt < 2; ++mt)
#pragma unroll
    for (int r = 0; r < 4; ++r) {
      const int m = m0 + wm * 32 + mt * 16 + quad * 4 + r;
#pragma unroll
      for (int nt = 0; nt < 4; ++nt) {
        const int n = n0 + wn * 64 + nt * 16 + lr;
        out[(size_t)m * 384 + n] = acc[mt][nt][r] + bv[nt];
      }
    }
}

// ---------------------------------------------------------------------------
extern "C" void kernel_launch(void* const* d_in, const int* in_sizes, int n_in,
                              void* d_out, int out_size, void* d_ws, size_t ws_size,
                              hipStream_t stream) {
  const float* x = (const float*)d_in[0];
  const float* qkv_w = (const float*)d_in[1];
  const float* qkv_b = (const float*)d_in[2];
  const float* pos = (const float*)d_in[3];
  const float* dwc_w = (const float*)d_in[4];
  const float* dwc_b = (const float*)d_in[5];
  const float* proj_w = (const float*)d_in[6];
  const float* proj_b = (const float*)d_in[7];
  float* out = (float*)d_out;

  // ws: q/y @0, kT @50331648, vT @100663296; total 150994944 B (144 MiB)
  const size_t WS_NEEDED = 150994944;
  if (ws_size < WS_NEEDED) return;  // diagnostic: absmax stays 1.1328125

  char* ws = (char*)d_ws;
  f16* q_ws = (f16*)(ws);                  // [3072][256][32], later y
  f16* kT_ws = (f16*)(ws + 50331648);      // [3072][32][256]
  f16* vT_ws = (f16*)(ws + 100663296);     // [3072][32][256]

  // f16 staging areas inside d_out (100.6 MB): xh [65536][384] = 50.3 MB,
  // qwh [1152][384] = 0.88 MB. Both dead before proj overwrites d_out.
  f16* xh = (f16*)d_out;
  f16* qwh = (f16*)((char*)d_out + 50331648);
  // proj_w f16 lives in the kT region (dead after attn_kernel).
  f16* pwh = (f16*)(ws + 50331648);

  cvt_kernel<<<2048, 256, 0, stream>>>(x, xh, 6291456);        // 96 MB read
  cvt_kernel<<<432, 256, 0, stream>>>(qkv_w, qwh, 110592);
  qkv_kernel<<<4608, 512, 0, stream>>>(xh, qwh, qkv_b, pos,
                                       q_ws, kT_ws, vT_ws);
  attn_kernel<<<3072, 256, 0, stream>>>(q_ws, kT_ws, vT_ws,
                                        dwc_w, dwc_b, q_ws /* y aliases q */);
  cvt_kernel<<<144, 256, 0, stream>>>(proj_w, pwh, 36864);
  proj_kernel<<<1536, 512, 0, stream>>>(q_ws, pwh, proj_b, out);
}